// Round 8
// baseline (279.098 us; speedup 1.0000x reference)
//
#include <hip/hip_runtime.h>
#include <stdint.h>

#define B_ 4
#define C_ 256
#define N_ 4096
#define LOG2E 1.44269504088896341f
#define EXP2(x) __builtin_amdgcn_exp2f(x)

typedef __attribute__((ext_vector_type(8))) short short8;
typedef __attribute__((ext_vector_type(4))) float f32x4;

__device__ __forceinline__ unsigned short f2bf(float f) {
    unsigned int u = __float_as_uint(f);
    u += 0x7FFFu + ((u >> 16) & 1u);
    return (unsigned short)(u >> 16);
}

// pack two f32 -> bf16 pair (round-half-up; inputs finite)
__device__ __forceinline__ unsigned int pack_bf(float a, float b) {
    return ((__float_as_uint(a) + 0x8000u) >> 16) |
           ((__float_as_uint(b) + 0x8000u) & 0xFFFF0000u);
}

// ---------------------------------------------------------------------------
// prep: pack W -> wb[320][256] bf16 (rows 0-31 Wq*(log2e/16), 32-63 Wk, 64-319 Wv)
// ---------------------------------------------------------------------------
__global__ __launch_bounds__(64) void prep_kernel(
    const float* __restrict__ Wq, const float* __restrict__ bq,
    const float* __restrict__ Wk, const float* __restrict__ bk,
    const float* __restrict__ Wv, const float* __restrict__ bv,
    unsigned short* __restrict__ wb, float* __restrict__ bb)
{
    const int m = blockIdx.x;
    const int t = threadIdx.x;
    const float* src;
    float scale = 1.0f, bias;
    if (m < 32)      { src = Wq + m * C_;        scale = 0.0625f * LOG2E; bias = bq[m] * 0.0625f * LOG2E; }
    else if (m < 64) { src = Wk + (m - 32) * C_;                          bias = bk[m - 32]; }
    else             { src = Wv + (m - 64) * C_;                          bias = bv[m - 64]; }
    float4 v = *(const float4*)(src + t * 4);
    unsigned int lo = (unsigned int)f2bf(v.x * scale) | ((unsigned int)f2bf(v.y * scale) << 16);
    unsigned int hi = (unsigned int)f2bf(v.z * scale) | ((unsigned int)f2bf(v.w * scale) << 16);
    *(uint2*)(wb + m * C_ + t * 4) = make_uint2(lo, hi);
    if (t == 0) bb[m] = bias;
}

// ---------------------------------------------------------------------------
// proj (MFMA GEMM): D[m][n] = sum_k wb[m][k] * x[b][k][n]  (+bias)
// ---------------------------------------------------------------------------
__global__ __launch_bounds__(256) void proj_kernel(
    const float* __restrict__ x,
    const unsigned short* __restrict__ wb, const float* __restrict__ bb,
    unsigned short* __restrict__ qT, unsigned short* __restrict__ kT,
    unsigned short* __restrict__ vb)
{
    __shared__ unsigned short xs[256][68];

    const int bid = ((blockIdx.x & 7) << 5) + (blockIdx.x >> 3);
    const int b = bid >> 6, n0 = (bid & 63) << 6;
    const int tid = threadIdx.x, wid = tid >> 6, lane = tid & 63;
    const int l15 = lane & 15, l4 = lane >> 4;

#pragma unroll
    for (int it = 0; it < 16; ++it) {
        int idx = it * 256 + tid;
        int k = idx >> 4, n4 = (idx & 15) << 2;
        float4 v = *(const float4*)(x + ((size_t)(b * C_ + k)) * N_ + n0 + n4);
        unsigned int lo = (unsigned int)f2bf(v.x) | ((unsigned int)f2bf(v.y) << 16);
        unsigned int hi = (unsigned int)f2bf(v.z) | ((unsigned int)f2bf(v.w) << 16);
        *(uint2*)&xs[k][n4] = make_uint2(lo, hi);
    }
    __syncthreads();

    const int m0 = wid * 80;
    f32x4 acc[5][4];
#pragma unroll
    for (int mf = 0; mf < 5; ++mf)
#pragma unroll
        for (int nt = 0; nt < 4; ++nt)
            acc[mf][nt] = (f32x4){0.f, 0.f, 0.f, 0.f};

#pragma unroll
    for (int s = 0; s < 8; ++s) {
        short8 wf[5];
#pragma unroll
        for (int mf = 0; mf < 5; ++mf)
            wf[mf] = *(const short8*)(wb + (size_t)(m0 + 16 * mf + l15) * C_ + 32 * s + 8 * l4);
        short8 xf[4];
#pragma unroll
        for (int nt = 0; nt < 4; ++nt) {
#pragma unroll
            for (int e = 0; e < 8; ++e)
                xf[nt][e] = (short)xs[32 * s + 8 * l4 + e][16 * nt + l15];
        }
#pragma unroll
        for (int mf = 0; mf < 5; ++mf)
#pragma unroll
            for (int nt = 0; nt < 4; ++nt)
                acc[mf][nt] = __builtin_amdgcn_mfma_f32_16x16x32_bf16(wf[mf], xf[nt], acc[mf][nt], 0, 0, 0);
    }

#pragma unroll
    for (int mf = 0; mf < 5; ++mf) {
        const int mbase = m0 + 16 * mf + 4 * l4;
        const float4 b4 = *(const float4*)(bb + mbase);
        const int region = (m0 + 16 * mf) >> 5;
#pragma unroll
        for (int nt = 0; nt < 4; ++nt) {
            const int n = n0 + 16 * nt + l15;
            float o0 = acc[mf][nt][0] + b4.x;
            float o1 = acc[mf][nt][1] + b4.y;
            float o2 = acc[mf][nt][2] + b4.z;
            float o3 = acc[mf][nt][3] + b4.w;
            if (region == 0) {
                *(uint2*)(qT + ((size_t)(b * N_ + n)) * 32 + mbase) =
                    make_uint2(pack_bf(o0, o1), pack_bf(o2, o3));
            } else if (region == 1) {
                *(uint2*)(kT + ((size_t)(b * N_ + n)) * 32 + (mbase - 32)) =
                    make_uint2(pack_bf(o0, o1), pack_bf(o2, o3));
            } else {
                const int c = mbase - 64;
                vb[((size_t)(b * C_ + c + 0)) * N_ + n] = f2bf(o0);
                vb[((size_t)(b * C_ + c + 1)) * N_ + n] = f2bf(o1);
                vb[((size_t)(b * C_ + c + 2)) * N_ + n] = f2bf(o2);
                vb[((size_t)(b * C_ + c + 3)) * N_ + n] = f2bf(o3);
            }
        }
    }
}

// ---------------------------------------------------------------------------
// attn: barrier-free flash attention, self-contained waves.
// grid 512 = (b, q-tile of 64, c-half) ; 256 threads = 4 independent waves.
// Wave: 16 q-rows (i0..i0+15) x 128 channels (c0..c0+127), all 64 KV tiles.
// Per tile: 4 QK MFMA -> in-lane softmax (2 shuffles) -> P via same-wave LDS
// round-trip (XOR-swizzled, lgkmcnt only) -> 16 PV MFMA, V direct from L2.
// No s_barrier anywhere. 2 blocks/CU -> 2 waves/SIMD.
// ---------------------------------------------------------------------------
__global__ __launch_bounds__(256, 2) void attn_kernel(
    const unsigned short* __restrict__ qT, const unsigned short* __restrict__ kT,
    const unsigned short* __restrict__ vbuf, const float* __restrict__ x,
    const float* __restrict__ gamma, float* __restrict__ out)
{
    __shared__ unsigned short Pl[4][16][64];   // per-wave P tile [q][kv], swizzled
    __shared__ float scl[4][16];               // per-wave scale/sum exchange row

    // XCD swizzle: 512 blocks, XCD r gets raw%8==r -> bids [64r,64r+64);
    // batch = bid>>7 -> each batch's V (2MB) pinned to one XCD pair's L2.
    const int raw = blockIdx.x;
    const int bid = ((raw & 7) << 6) | (raw >> 3);
    const int b   = bid >> 7;
    const int rem = bid & 127;
    const int qt = rem >> 1, ch = rem & 1;
    const int tid = threadIdx.x, wid = tid >> 6, lane = tid & 63;
    const int q = lane & 15, h = lane >> 4;
    const int c0 = ch << 7;
    const int i0 = qt * 64 + wid * 16;

    const f32x4 zero = {0.f, 0.f, 0.f, 0.f};

    // Q A..B-frag: col=q -> q-row i0+q, k = 8h+e
    const short8 qfrag = *(const short8*)(qT + ((size_t)(b * N_ + i0 + q)) * 32 + 8 * h);
    const unsigned short* kbase = kT + ((size_t)b * N_ + q) * 32 + 8 * h;            // + j*32
    const unsigned short* vbase = vbuf + ((size_t)(b * C_ + c0 + q)) * N_ + 8 * h;   // + 16cb*N + kv

    unsigned short* Pb = &Pl[wid][0][0];
    const int pbase = q << 6;             // ush offset of row q (64 ush = 128B)
    const int pswz  = (q & 7) << 3;       // XOR on 16B granules (8 ush)

    short8 ka[4], kn[4];
#pragma unroll
    for (int f = 0; f < 4; ++f)
        ka[f] = *(const short8*)(kbase + (size_t)(16 * f) * 32);

    f32x4 acc[8];
#pragma unroll
    for (int cb = 0; cb < 8; ++cb) acc[cb] = zero;
    float m = -1e30f, l = 0.f;

    for (int t = 0; t < 64; ++t) {
        // ---- V loads for this tile (no dep on S; fly during QK+softmax) ----
        short8 vfa[8], vfb[8];
#pragma unroll
        for (int cb = 0; cb < 8; ++cb)
            vfa[cb] = *(const short8*)(vbase + (size_t)(16 * cb) * N_ + t * 64);
#pragma unroll
        for (int cb = 0; cb < 8; ++cb)
            vfb[cb] = *(const short8*)(vbase + (size_t)(16 * cb) * N_ + t * 64 + 32);

        // ---- QK^T (swapped): sv[f][r] = S[q][kv=16f+4h+r] ----
        f32x4 sv[4];
#pragma unroll
        for (int f = 0; f < 4; ++f)
            sv[f] = __builtin_amdgcn_mfma_f32_16x16x32_bf16(ka[f], qfrag, zero, 0, 0, 0);

        // ---- K prefetch for next tile ----
        if (t < 63) {
#pragma unroll
            for (int f = 0; f < 4; ++f)
                kn[f] = *(const short8*)(kbase + (size_t)((t + 1) * 64 + 16 * f) * 32);
        }

        // ---- online softmax (row q; 16 in-lane values + lanes q,q+16,q+32,q+48) ----
        float m4[4];
#pragma unroll
        for (int f = 0; f < 4; ++f)
            m4[f] = fmaxf(fmaxf(sv[f][0], sv[f][1]), fmaxf(sv[f][2], sv[f][3]));
        float mx = fmaxf(fmaxf(m4[0], m4[1]), fmaxf(m4[2], m4[3]));
        mx = fmaxf(mx, __shfl_xor(mx, 16, 64));
        mx = fmaxf(mx, __shfl_xor(mx, 32, 64));
        const float mn = fmaxf(m, mx);
        const float scf = EXP2(m - mn);
        m = mn;
#pragma unroll
        for (int f = 0; f < 4; ++f)
#pragma unroll
            for (int r = 0; r < 4; ++r) sv[f][r] = EXP2(sv[f][r] - mn);
        float s4[4];
#pragma unroll
        for (int f = 0; f < 4; ++f)
            s4[f] = (sv[f][0] + sv[f][1]) + (sv[f][2] + sv[f][3]);
        float ps = (s4[0] + s4[1]) + (s4[2] + s4[3]);
        ps += __shfl_xor(ps, 16, 64);
        ps += __shfl_xor(ps, 32, 64);
        l = l * scf + ps;

        // ---- P -> per-wave LDS (swizzled), publish scf ----
#pragma unroll
        for (int f = 0; f < 4; ++f)
            *(uint2*)(Pb + ((pbase + 16 * f + 4 * h) ^ pswz)) =
                make_uint2(pack_bf(sv[f][0], sv[f][1]), pack_bf(sv[f][2], sv[f][3]));
        if (lane < 16) scl[wid][q] = scf;

        asm volatile("s_waitcnt lgkmcnt(0)" ::: "memory");   // same-wave LDS RAW

        // ---- read PA frags (A: row=q, k=8h+e) + redistributed scales ----
        short8 pa0 = *(const short8*)(Pb + ((pbase + 8 * h) ^ pswz));
        short8 pa1 = *(const short8*)(Pb + ((pbase + 32 + 8 * h) ^ pswz));
        f32x4 scv = *(const f32x4*)&scl[wid][4 * h];

        bool need = (scv[0] != 1.f) | (scv[1] != 1.f) | (scv[2] != 1.f) | (scv[3] != 1.f);
        if (__any(need)) {
#pragma unroll
            for (int cb = 0; cb < 8; ++cb)
#pragma unroll
                for (int r = 0; r < 4; ++r) acc[cb][r] *= scv[r];
        }

        // ---- PV: acc[cb] rows 4h+r (q-rows), cols 16cb+q (channels) ----
#pragma unroll
        for (int cb = 0; cb < 8; ++cb)
            acc[cb] = __builtin_amdgcn_mfma_f32_16x16x32_bf16(pa0, vfa[cb], acc[cb], 0, 0, 0);
#pragma unroll
        for (int cb = 0; cb < 8; ++cb)
            acc[cb] = __builtin_amdgcn_mfma_f32_16x16x32_bf16(pa1, vfb[cb], acc[cb], 0, 0, 0);

#pragma unroll
        for (int f = 0; f < 4; ++f) ka[f] = kn[f];
    }

    // ---- epilogue: out = gamma/l * acc + x ----
    if (lane < 16) scl[wid][q] = l;
    asm volatile("s_waitcnt lgkmcnt(0)" ::: "memory");
    const f32x4 lv = *(const f32x4*)&scl[wid][4 * h];
    const float gm = gamma[0];
    float inv[4];
#pragma unroll
    for (int r = 0; r < 4; ++r) inv[r] = gm / lv[r];
#pragma unroll
    for (int cb = 0; cb < 8; ++cb) {
        const size_t oidx = ((size_t)(b * C_ + c0 + 16 * cb + q)) * N_ + i0 + 4 * h;
        const float4 xr = *(const float4*)(x + oidx);
        float4 res;
        res.x = acc[cb][0] * inv[0] + xr.x;
        res.y = acc[cb][1] * inv[1] + xr.y;
        res.z = acc[cb][2] * inv[2] + xr.z;
        res.w = acc[cb][3] * inv[3] + xr.w;
        *(float4*)(out + oidx) = res;
    }
}

extern "C" void kernel_launch(void* const* d_in, const int* in_sizes, int n_in,
                              void* d_out, int out_size, void* d_ws, size_t ws_size,
                              hipStream_t stream) {
    (void)in_sizes; (void)n_in; (void)out_size; (void)ws_size;
    const float* x  = (const float*)d_in[0];
    const float* Wq = (const float*)d_in[1];
    const float* bq = (const float*)d_in[2];
    const float* Wk = (const float*)d_in[3];
    const float* bk = (const float*)d_in[4];
    const float* Wv = (const float*)d_in[5];
    const float* bv = (const float*)d_in[6];
    const float* gm = (const float*)d_in[7];
    float* out = (float*)d_out;

    char* ws = (char*)d_ws;
    unsigned short* wb = (unsigned short*)ws;                                // 160 KB
    float*          bb = (float*)(ws + 320 * 256 * 2);                       // 1.25 KB
    unsigned short* qT = (unsigned short*)(ws + 320 * 256 * 2 + 320 * 4);    // 1 MB
    unsigned short* kT = qT + (size_t)B_ * N_ * 32;                          // 1 MB
    unsigned short* vb = kT + (size_t)B_ * N_ * 32;                          // 8 MB

    hipLaunchKernelGGL(prep_kernel, dim3(320), dim3(64), 0, stream,
                       Wq, bq, Wk, bk, Wv, bv, wb, bb);
    hipLaunchKernelGGL(proj_kernel, dim3(256), dim3(256), 0, stream,
                       x, wb, bb, qT, kT, vb);
    hipLaunchKernelGGL(attn_kernel, dim3(512), dim3(256), 0, stream,
                       qT, kT, vb, x, gm, out);
}

// Round 9
// 221.117 us; speedup vs baseline: 1.2622x; 1.2622x over previous
//
#include <hip/hip_runtime.h>
#include <stdint.h>

#define B_ 4
#define C_ 256
#define N_ 4096
#define LOG2E 1.44269504088896341f
#define EXP2(x) __builtin_amdgcn_exp2f(x)

typedef __attribute__((ext_vector_type(8))) short short8;
typedef __attribute__((ext_vector_type(4))) float f32x4;
typedef __attribute__((ext_vector_type(16))) float f32x16;

union frag_u { short8 s; unsigned int u[4]; };

__device__ __forceinline__ unsigned short f2bf(float f) {
    unsigned int u = __float_as_uint(f);
    u += 0x7FFFu + ((u >> 16) & 1u);
    return (unsigned short)(u >> 16);
}

// pack two f32 -> 2 bf16 in one u32 (round-half-up) via v_perm_b32
__device__ __forceinline__ unsigned int pack_bf(float a, float b) {
    unsigned int ua = __float_as_uint(a) + 0x8000u;
    unsigned int ub = __float_as_uint(b) + 0x8000u;
    return __builtin_amdgcn_perm(ub, ua, 0x07060302u);  // [b_hi16 | a_hi16]
}

// pin a 128-bit value in VGPRs at this point (defeats load sinking, r8 lesson)
__device__ __forceinline__ void pin(short8& v) {
    int4 t = *reinterpret_cast<int4*>(&v);
    asm volatile("" : "+v"(t.x), "+v"(t.y), "+v"(t.z), "+v"(t.w));
    *reinterpret_cast<int4*>(&v) = t;
}

// ---------------------------------------------------------------------------
// prep: pack W -> wb[320][256] bf16 (rows 0-31 Wq*(log2e/16), 32-63 Wk, 64-319 Wv)
// ---------------------------------------------------------------------------
__global__ __launch_bounds__(64) void prep_kernel(
    const float* __restrict__ Wq, const float* __restrict__ bq,
    const float* __restrict__ Wk, const float* __restrict__ bk,
    const float* __restrict__ Wv, const float* __restrict__ bv,
    unsigned short* __restrict__ wb, float* __restrict__ bb)
{
    const int m = blockIdx.x;
    const int t = threadIdx.x;
    const float* src;
    float scale = 1.0f, bias;
    if (m < 32)      { src = Wq + m * C_;        scale = 0.0625f * LOG2E; bias = bq[m] * 0.0625f * LOG2E; }
    else if (m < 64) { src = Wk + (m - 32) * C_;                          bias = bk[m - 32]; }
    else             { src = Wv + (m - 64) * C_;                          bias = bv[m - 64]; }
    float4 v = *(const float4*)(src + t * 4);
    unsigned int lo = (unsigned int)f2bf(v.x * scale) | ((unsigned int)f2bf(v.y * scale) << 16);
    unsigned int hi = (unsigned int)f2bf(v.z * scale) | ((unsigned int)f2bf(v.w * scale) << 16);
    *(uint2*)(wb + m * C_ + t * 4) = make_uint2(lo, hi);
    if (t == 0) bb[m] = bias;
}

// ---------------------------------------------------------------------------
// proj (MFMA GEMM): D[m][n] = sum_k wb[m][k] * x[b][k][n]  (+bias)
// ---------------------------------------------------------------------------
__global__ __launch_bounds__(256) void proj_kernel(
    const float* __restrict__ x,
    const unsigned short* __restrict__ wb, const float* __restrict__ bb,
    unsigned short* __restrict__ qT, unsigned short* __restrict__ kT,
    unsigned short* __restrict__ vb)
{
    __shared__ unsigned short xs[256][68];

    const int bid = ((blockIdx.x & 7) << 5) + (blockIdx.x >> 3);
    const int b = bid >> 6, n0 = (bid & 63) << 6;
    const int tid = threadIdx.x, wid = tid >> 6, lane = tid & 63;
    const int l15 = lane & 15, l4 = lane >> 4;

#pragma unroll
    for (int it = 0; it < 16; ++it) {
        int idx = it * 256 + tid;
        int k = idx >> 4, n4 = (idx & 15) << 2;
        float4 v = *(const float4*)(x + ((size_t)(b * C_ + k)) * N_ + n0 + n4);
        unsigned int lo = (unsigned int)f2bf(v.x) | ((unsigned int)f2bf(v.y) << 16);
        unsigned int hi = (unsigned int)f2bf(v.z) | ((unsigned int)f2bf(v.w) << 16);
        *(uint2*)&xs[k][n4] = make_uint2(lo, hi);
    }
    __syncthreads();

    const int m0 = wid * 80;
    f32x4 acc[5][4];
#pragma unroll
    for (int mf = 0; mf < 5; ++mf)
#pragma unroll
        for (int nt = 0; nt < 4; ++nt)
            acc[mf][nt] = (f32x4){0.f, 0.f, 0.f, 0.f};

#pragma unroll
    for (int s = 0; s < 8; ++s) {
        short8 wf[5];
#pragma unroll
        for (int mf = 0; mf < 5; ++mf)
            wf[mf] = *(const short8*)(wb + (size_t)(m0 + 16 * mf + l15) * C_ + 32 * s + 8 * l4);
        short8 xf[4];
#pragma unroll
        for (int nt = 0; nt < 4; ++nt) {
#pragma unroll
            for (int e = 0; e < 8; ++e)
                xf[nt][e] = (short)xs[32 * s + 8 * l4 + e][16 * nt + l15];
        }
#pragma unroll
        for (int mf = 0; mf < 5; ++mf)
#pragma unroll
            for (int nt = 0; nt < 4; ++nt)
                acc[mf][nt] = __builtin_amdgcn_mfma_f32_16x16x32_bf16(wf[mf], xf[nt], acc[mf][nt], 0, 0, 0);
    }

#pragma unroll
    for (int mf = 0; mf < 5; ++mf) {
        const int mbase = m0 + 16 * mf + 4 * l4;
        const float4 b4 = *(const float4*)(bb + mbase);
        const int region = (m0 + 16 * mf) >> 5;
#pragma unroll
        for (int nt = 0; nt < 4; ++nt) {
            const int n = n0 + 16 * nt + l15;
            float o0 = acc[mf][nt][0] + b4.x;
            float o1 = acc[mf][nt][1] + b4.y;
            float o2 = acc[mf][nt][2] + b4.z;
            float o3 = acc[mf][nt][3] + b4.w;
            if (region == 0) {
                *(uint2*)(qT + ((size_t)(b * N_ + n)) * 32 + mbase) =
                    make_uint2(pack_bf(o0, o1), pack_bf(o2, o3));
            } else if (region == 1) {
                *(uint2*)(kT + ((size_t)(b * N_ + n)) * 32 + (mbase - 32)) =
                    make_uint2(pack_bf(o0, o1), pack_bf(o2, o3));
            } else {
                const int c = mbase - 64;
                vb[((size_t)(b * C_ + c + 0)) * N_ + n] = f2bf(o0);
                vb[((size_t)(b * C_ + c + 1)) * N_ + n] = f2bf(o1);
                vb[((size_t)(b * C_ + c + 2)) * N_ + n] = f2bf(o2);
                vb[((size_t)(b * C_ + c + 3)) * N_ + n] = f2bf(o3);
            }
        }
    }
}

// ---------------------------------------------------------------------------
// attn: barrier-free flash attention, 32x32 MFMA, in-register P exchange.
// grid 256 = (b, q-tile of 64); 512 threads = 8 independent waves.
// Wave w: q-rows [i0 + (w&1)*32, +32), channels [(w>>1)*64, +64).
// Per tile 64: V loads (pinned) -> swapped QK (4 MFMA, S[kv][q], q=lane&31)
//   -> in-lane softmax (1 shfl_xor32 for max, 1 for sum)
//   -> pack bf16 quads -> 8 shfl_xor32 builds PV A-frags (no LDS, no barrier)
//   -> guarded rescale (scales via per-wave-private LDS row, in-order DS)
//   -> 8 PV MFMA (V direct from L2).
// ---------------------------------------------------------------------------
__global__ __launch_bounds__(512, 2) void attn_kernel(
    const unsigned short* __restrict__ qT, const unsigned short* __restrict__ kT,
    const unsigned short* __restrict__ vbuf, const float* __restrict__ x,
    const float* __restrict__ gamma, float* __restrict__ out)
{
    __shared__ float scl[8][32];   // per-wave private scale/denominator row

    const int raw = blockIdx.x;
    const int bid = ((raw & 7) << 5) | (raw >> 3);   // batch -> 2 XCDs (V L2-pinned)
    const int b = bid >> 6;
    const int i0 = (bid & 63) << 6;
    const int tid = threadIdx.x, wid = tid >> 6, lane = tid & 63;
    const int q = lane & 31, h = lane >> 5;
    const int iq = i0 + (wid & 1) * 32;
    const int c0w = (wid >> 1) << 6;

    // Q B-frags (col=q, k=8h+e ; two k-steps for CQ=32)
    const unsigned short* qrow = qT + ((size_t)(b * N_ + iq + q)) * 32 + 8 * h;
    const short8 qf0 = *(const short8*)(qrow);
    const short8 qf1 = *(const short8*)(qrow + 16);

    const unsigned short* kbase = kT + ((size_t)b * N_ + q) * 32 + 8 * h;
    const unsigned short* vrow0 = vbuf + ((size_t)(b * C_ + c0w + q)) * N_ + 8 * h;
    const unsigned short* vrow1 = vbuf + ((size_t)(b * C_ + c0w + 32 + q)) * N_ + 8 * h;

    // K frags: [blk*2+kk], rows blk*32+q, k = kk*16 + 8h
    short8 ka[4], kn[4];
#pragma unroll
    for (int f = 0; f < 4; ++f)
        ka[f] = *(const short8*)(kbase + (f >> 1) * 1024 + (f & 1) * 16);

    f32x16 acc0, acc1, zero16;
#pragma unroll
    for (int r = 0; r < 16; ++r) { acc0[r] = 0.f; acc1[r] = 0.f; zero16[r] = 0.f; }
    float m = -1e30f, l = 0.f;

    for (int t = 0; t < 64; ++t) {
        // ---- V loads for this tile (issued first; pinned so they can't sink) ----
        short8 vf[4][2];
#pragma unroll
        for (int mm = 0; mm < 4; ++mm) {
            vf[mm][0] = *(const short8*)(vrow0 + t * 64 + mm * 16);
            vf[mm][1] = *(const short8*)(vrow1 + t * 64 + mm * 16);
            pin(vf[mm][0]); pin(vf[mm][1]);
        }

        // ---- swapped QK: sv[blk] = S[kv_local][q], kv = 32blk + (r&3)+8(r>>2)+4h ----
        f32x16 sv0 = __builtin_amdgcn_mfma_f32_32x32x16_bf16(ka[0], qf0, zero16, 0, 0, 0);
        sv0 = __builtin_amdgcn_mfma_f32_32x32x16_bf16(ka[1], qf1, sv0, 0, 0, 0);
        f32x16 sv1 = __builtin_amdgcn_mfma_f32_32x32x16_bf16(ka[2], qf0, zero16, 0, 0, 0);
        sv1 = __builtin_amdgcn_mfma_f32_32x32x16_bf16(ka[3], qf1, sv1, 0, 0, 0);

        // ---- K prefetch for next tile ----
        if (t < 63) {
#pragma unroll
            for (int f = 0; f < 4; ++f) {
                kn[f] = *(const short8*)(kbase + (t + 1) * 2048 + (f >> 1) * 1024 + (f & 1) * 16);
                pin(kn[f]);
            }
        }

        // ---- online softmax for row q (32 in-lane values + partner l^32) ----
        float t16[16];
#pragma unroll
        for (int r = 0; r < 16; ++r) t16[r] = fmaxf(sv0[r], sv1[r]);
#pragma unroll
        for (int r = 0; r < 8; ++r) t16[r] = fmaxf(t16[r], t16[r + 8]);
#pragma unroll
        for (int r = 0; r < 4; ++r) t16[r] = fmaxf(t16[r], t16[r + 4]);
        float mx = fmaxf(fmaxf(t16[0], t16[1]), fmaxf(t16[2], t16[3]));
        mx = fmaxf(mx, __shfl_xor(mx, 32, 64));
        const float mn = fmaxf(m, mx);
        const float scf = EXP2(m - mn);
        m = mn;
        if (h == 0) scl[wid][q] = scf;

#pragma unroll
        for (int r = 0; r < 16; ++r) { sv0[r] = EXP2(sv0[r] - mn); sv1[r] = EXP2(sv1[r] - mn); }
        float u16[16];
#pragma unroll
        for (int r = 0; r < 16; ++r) u16[r] = sv0[r] + sv1[r];
#pragma unroll
        for (int r = 0; r < 8; ++r) u16[r] += u16[r + 8];
#pragma unroll
        for (int r = 0; r < 4; ++r) u16[r] += u16[r + 4];
        float ps = (u16[0] + u16[1]) + (u16[2] + u16[3]);
        ps += __shfl_xor(ps, 32, 64);
        l = l * scf + ps;

        // ---- pack P quads: P0/P1[blk][s] = kv {8s+4h + 0..1 / 2..3} ----
        unsigned int P0[2][4], P1[2][4];
#pragma unroll
        for (int s = 0; s < 4; ++s) {
            P0[0][s] = pack_bf(sv0[4 * s], sv0[4 * s + 1]);
            P1[0][s] = pack_bf(sv0[4 * s + 2], sv0[4 * s + 3]);
            P0[1][s] = pack_bf(sv1[4 * s], sv1[4 * s + 1]);
            P1[1][s] = pack_bf(sv1[4 * s + 2], sv1[4 * s + 3]);
        }

        // ---- build PV A-frags pa[m]: P[q][16m+8h .. +7] via lane^32 exchange ----
        short8 pa[4];
#pragma unroll
        for (int mm = 0; mm < 4; ++mm) {
            const int blk = mm >> 1, se = 2 * (mm & 1);
            unsigned int e0 = P0[blk][se],     e1 = P1[blk][se];      // even quad (lo-type)
            unsigned int o0 = P0[blk][se + 1], o1 = P1[blk][se + 1];  // odd quad (hi-type)
            unsigned int s0 = h ? e0 : o0;   // what partner needs
            unsigned int s1 = h ? e1 : o1;
            unsigned int r0 = __shfl_xor(s0, 32, 64);
            unsigned int r1 = __shfl_xor(s1, 32, 64);
            frag_u f;
            f.u[0] = h ? r0 : e0;  f.u[1] = h ? r1 : e1;   // lo quad (kv 16m+8h+0..3)
            f.u[2] = h ? o0 : r0;  f.u[3] = h ? o1 : r1;   // hi quad (kv 16m+8h+4..7)
            pa[mm] = f.s;
        }

        // ---- rescale acc (scales for rows (reg&3)+8(reg>>2)+4h via LDS row) ----
        if (__any(scf != 1.0f)) {
            f32x4 s0 = *(const f32x4*)&scl[wid][4 * h];
            f32x4 s1 = *(const f32x4*)&scl[wid][8 + 4 * h];
            f32x4 s2 = *(const f32x4*)&scl[wid][16 + 4 * h];
            f32x4 s3 = *(const f32x4*)&scl[wid][24 + 4 * h];
#pragma unroll
            for (int r = 0; r < 4; ++r) {
                acc0[r] *= s0[r];      acc1[r] *= s0[r];
                acc0[4 + r] *= s1[r];  acc1[4 + r] *= s1[r];
                acc0[8 + r] *= s2[r];  acc1[8 + r] *= s2[r];
                acc0[12 + r] *= s3[r]; acc1[12 + r] *= s3[r];
            }
        }

        // ---- PV: D[q][c] += P[q][kv] * V[c][kv] ----
#pragma unroll
        for (int mm = 0; mm < 4; ++mm) {
            acc0 = __builtin_amdgcn_mfma_f32_32x32x16_bf16(pa[mm], vf[mm][0], acc0, 0, 0, 0);
            acc1 = __builtin_amdgcn_mfma_f32_32x32x16_bf16(pa[mm], vf[mm][1], acc1, 0, 0, 0);
        }

#pragma unroll
        for (int f = 0; f < 4; ++f) ka[f] = kn[f];
    }

    // ---- epilogue: out = gamma/l * acc + x ----
    if (h == 0) scl[wid][q] = l;
    const float gm = gamma[0];
    f32x4 lv[4];
    lv[0] = *(const f32x4*)&scl[wid][4 * h];
    lv[1] = *(const f32x4*)&scl[wid][8 + 4 * h];
    lv[2] = *(const f32x4*)&scl[wid][16 + 4 * h];
    lv[3] = *(const f32x4*)&scl[wid][24 + 4 * h];
    float inv[4][4];
#pragma unroll
    for (int s = 0; s < 4; ++s)
#pragma unroll
        for (int r = 0; r < 4; ++r) inv[s][r] = gm / lv[s][r];

#pragma unroll
    for (int cf = 0; cf < 2; ++cf) {
        const int c = c0w + 32 * cf + q;
#pragma unroll
        for (int s = 0; s < 4; ++s) {
            const size_t oidx = ((size_t)(b * C_ + c)) * N_ + iq + 8 * s + 4 * h;
            const float4 xr = *(const float4*)(x + oidx);
            float4 res;
            const float a0 = cf ? acc1[4 * s + 0] : acc0[4 * s + 0];
            const float a1 = cf ? acc1[4 * s + 1] : acc0[4 * s + 1];
            const float a2 = cf ? acc1[4 * s + 2] : acc0[4 * s + 2];
            const float a3 = cf ? acc1[4 * s + 3] : acc0[4 * s + 3];
            res.x = a0 * inv[s][0] + xr.x;
            res.y = a1 * inv[s][1] + xr.y;
            res.z = a2 * inv[s][2] + xr.z;
            res.w = a3 * inv[s][3] + xr.w;
            *(float4*)(out + oidx) = res;
        }
    }
}

extern "C" void kernel_launch(void* const* d_in, const int* in_sizes, int n_in,
                              void* d_out, int out_size, void* d_ws, size_t ws_size,
                              hipStream_t stream) {
    (void)in_sizes; (void)n_in; (void)out_size; (void)ws_size;
    const float* x  = (const float*)d_in[0];
    const float* Wq = (const float*)d_in[1];
    const float* bq = (const float*)d_in[2];
    const float* Wk = (const float*)d_in[3];
    const float* bk = (const float*)d_in[4];
    const float* Wv = (const float*)d_in[5];
    const float* bv = (const float*)d_in[6];
    const float* gm = (const float*)d_in[7];
    float* out = (float*)d_out;

    char* ws = (char*)d_ws;
    unsigned short* wb = (unsigned short*)ws;                                // 160 KB
    float*          bb = (float*)(ws + 320 * 256 * 2);                       // 1.25 KB
    unsigned short* qT = (unsigned short*)(ws + 320 * 256 * 2 + 320 * 4);    // 1 MB
    unsigned short* kT = qT + (size_t)B_ * N_ * 32;                          // 1 MB
    unsigned short* vb = kT + (size_t)B_ * N_ * 32;                          // 8 MB

    hipLaunchKernelGGL(prep_kernel, dim3(320), dim3(64), 0, stream,
                       Wq, bq, Wk, bk, Wv, bv, wb, bb);
    hipLaunchKernelGGL(proj_kernel, dim3(256), dim3(256), 0, stream,
                       x, wb, bb, qT, kT, vb);
    hipLaunchKernelGGL(attn_kernel, dim3(256), dim3(512), 0, stream,
                       qT, kT, vb, x, gm, out);
}

// Round 10
// 191.118 us; speedup vs baseline: 1.4603x; 1.1570x over previous
//
#include <hip/hip_runtime.h>
#include <stdint.h>

#define B_ 4
#define C_ 256
#define N_ 4096
#define LOG2E 1.44269504088896341f
#define EXP2(x) __builtin_amdgcn_exp2f(x)

typedef __attribute__((ext_vector_type(8))) short short8;
typedef __attribute__((ext_vector_type(4))) float f32x4;
typedef __attribute__((ext_vector_type(16))) float f32x16;

union frag_u { short8 s; unsigned int u[4]; };

__device__ __forceinline__ unsigned short f2bf(float f) {
    unsigned int u = __float_as_uint(f);
    u += 0x7FFFu + ((u >> 16) & 1u);
    return (unsigned short)(u >> 16);
}

// pack two f32 -> 2 bf16 in one u32 (round-half-up) via v_perm_b32
__device__ __forceinline__ unsigned int pack_bf(float a, float b) {
    unsigned int ua = __float_as_uint(a) + 0x8000u;
    unsigned int ub = __float_as_uint(b) + 0x8000u;
    return __builtin_amdgcn_perm(ub, ua, 0x07060302u);  // [b_hi16 | a_hi16]
}

// barrier: drain LDS writes, raw barrier (global loads may stay in flight)
#define BAR() do { \
    asm volatile("s_waitcnt lgkmcnt(0)" ::: "memory"); \
    __builtin_amdgcn_s_barrier(); \
    asm volatile("" ::: "memory"); } while (0)

// ---------------------------------------------------------------------------
// prep: pack W -> wb[320][256] bf16 (rows 0-31 Wq*(log2e/16), 32-63 Wk, 64-319 Wv)
// ---------------------------------------------------------------------------
__global__ __launch_bounds__(64) void prep_kernel(
    const float* __restrict__ Wq, const float* __restrict__ bq,
    const float* __restrict__ Wk, const float* __restrict__ bk,
    const float* __restrict__ Wv, const float* __restrict__ bv,
    unsigned short* __restrict__ wb, float* __restrict__ bb)
{
    const int m = blockIdx.x;
    const int t = threadIdx.x;
    const float* src;
    float scale = 1.0f, bias;
    if (m < 32)      { src = Wq + m * C_;        scale = 0.0625f * LOG2E; bias = bq[m] * 0.0625f * LOG2E; }
    else if (m < 64) { src = Wk + (m - 32) * C_;                          bias = bk[m - 32]; }
    else             { src = Wv + (m - 64) * C_;                          bias = bv[m - 64]; }
    float4 v = *(const float4*)(src + t * 4);
    unsigned int lo = (unsigned int)f2bf(v.x * scale) | ((unsigned int)f2bf(v.y * scale) << 16);
    unsigned int hi = (unsigned int)f2bf(v.z * scale) | ((unsigned int)f2bf(v.w * scale) << 16);
    *(uint2*)(wb + m * C_ + t * 4) = make_uint2(lo, hi);
    if (t == 0) bb[m] = bias;
}

// ---------------------------------------------------------------------------
// proj (MFMA GEMM): D[m][n] = sum_k wb[m][k] * x[b][k][n]  (+bias)
// ---------------------------------------------------------------------------
__global__ __launch_bounds__(256) void proj_kernel(
    const float* __restrict__ x,
    const unsigned short* __restrict__ wb, const float* __restrict__ bb,
    unsigned short* __restrict__ qT, unsigned short* __restrict__ kT,
    unsigned short* __restrict__ vb)
{
    __shared__ unsigned short xs[256][68];

    const int bid = ((blockIdx.x & 7) << 5) + (blockIdx.x >> 3);
    const int b = bid >> 6, n0 = (bid & 63) << 6;
    const int tid = threadIdx.x, wid = tid >> 6, lane = tid & 63;
    const int l15 = lane & 15, l4 = lane >> 4;

#pragma unroll
    for (int it = 0; it < 16; ++it) {
        int idx = it * 256 + tid;
        int k = idx >> 4, n4 = (idx & 15) << 2;
        float4 v = *(const float4*)(x + ((size_t)(b * C_ + k)) * N_ + n0 + n4);
        unsigned int lo = (unsigned int)f2bf(v.x) | ((unsigned int)f2bf(v.y) << 16);
        unsigned int hi = (unsigned int)f2bf(v.z) | ((unsigned int)f2bf(v.w) << 16);
        *(uint2*)&xs[k][n4] = make_uint2(lo, hi);
    }
    __syncthreads();

    const int m0 = wid * 80;
    f32x4 acc[5][4];
#pragma unroll
    for (int mf = 0; mf < 5; ++mf)
#pragma unroll
        for (int nt = 0; nt < 4; ++nt)
            acc[mf][nt] = (f32x4){0.f, 0.f, 0.f, 0.f};

#pragma unroll
    for (int s = 0; s < 8; ++s) {
        short8 wf[5];
#pragma unroll
        for (int mf = 0; mf < 5; ++mf)
            wf[mf] = *(const short8*)(wb + (size_t)(m0 + 16 * mf + l15) * C_ + 32 * s + 8 * l4);
        short8 xf[4];
#pragma unroll
        for (int nt = 0; nt < 4; ++nt) {
#pragma unroll
            for (int e = 0; e < 8; ++e)
                xf[nt][e] = (short)xs[32 * s + 8 * l4 + e][16 * nt + l15];
        }
#pragma unroll
        for (int mf = 0; mf < 5; ++mf)
#pragma unroll
            for (int nt = 0; nt < 4; ++nt)
                acc[mf][nt] = __builtin_amdgcn_mfma_f32_16x16x32_bf16(wf[mf], xf[nt], acc[mf][nt], 0, 0, 0);
    }

#pragma unroll
    for (int mf = 0; mf < 5; ++mf) {
        const int mbase = m0 + 16 * mf + 4 * l4;
        const float4 b4 = *(const float4*)(bb + mbase);
        const int region = (m0 + 16 * mf) >> 5;
#pragma unroll
        for (int nt = 0; nt < 4; ++nt) {
            const int n = n0 + 16 * nt + l15;
            float o0 = acc[mf][nt][0] + b4.x;
            float o1 = acc[mf][nt][1] + b4.y;
            float o2 = acc[mf][nt][2] + b4.z;
            float o3 = acc[mf][nt][3] + b4.w;
            if (region == 0) {
                *(uint2*)(qT + ((size_t)(b * N_ + n)) * 32 + mbase) =
                    make_uint2(pack_bf(o0, o1), pack_bf(o2, o3));
            } else if (region == 1) {
                *(uint2*)(kT + ((size_t)(b * N_ + n)) * 32 + (mbase - 32)) =
                    make_uint2(pack_bf(o0, o1), pack_bf(o2, o3));
            } else {
                const int c = mbase - 64;
                vb[((size_t)(b * C_ + c + 0)) * N_ + n] = f2bf(o0);
                vb[((size_t)(b * C_ + c + 1)) * N_ + n] = f2bf(o1);
                vb[((size_t)(b * C_ + c + 2)) * N_ + n] = f2bf(o2);
                vb[((size_t)(b * C_ + c + 3)) * N_ + n] = f2bf(o3);
            }
        }
    }
}

// ---------------------------------------------------------------------------
// attn: flash attention, 32x32 MFMA, in-register P exchange, LDS-staged K/V.
// grid 256 = (b, q-tile of 64); 512 threads = 8 uniform waves.
// Wave w: q-rows [i0+(w&1)*32, +32), channels [(w>>1)*64, +64).
// Per KV-tile (64): issue coalesced global loads for tile t+1 (T14 early) ->
//   QK from Kl (padded LDS) -> in-lane softmax -> vmcnt + swizzled ds_write of
//   t+1 -> P exchange via shfl_xor32 (no LDS) -> guarded rescale ->
//   PV from Vl (XOR-swizzled ds_read_b128) -> one barrier.
// ---------------------------------------------------------------------------
__global__ __launch_bounds__(512, 2) void attn_kernel(
    const unsigned short* __restrict__ qT, const unsigned short* __restrict__ kT,
    const unsigned short* __restrict__ vbuf, const float* __restrict__ x,
    const float* __restrict__ gamma, float* __restrict__ out)
{
    __shared__ unsigned short Vl[2][256][64];  // [buf][c][kv] XOR-swizzled granules
    __shared__ unsigned short Kl[2][64][40];   // [buf][kv][k] padded rows (80B)
    __shared__ float scl[8][32];               // per-wave private scale/denom row

    const int raw = blockIdx.x;
    const int bid = ((raw & 7) << 5) | (raw >> 3);   // batch -> 2 XCDs (KV L2-pinned)
    const int b = bid >> 6;
    const int i0 = (bid & 63) << 6;
    const int tid = threadIdx.x, wid = tid >> 6, lane = tid & 63;
    const int q = lane & 31, h = lane >> 5;
    const int iq = i0 + (wid & 1) * 32;
    const int c0w = (wid >> 1) << 6;

    // Q B-frags (col=q -> q-row iq+q, k = 16kk + 8h + e)
    const unsigned short* qrow = qT + ((size_t)(b * N_ + iq + q)) * 32 + 8 * h;
    const short8 qf0 = *(const short8*)(qrow);
    const short8 qf1 = *(const short8*)(qrow + 16);

    // staging: V granules (16B): thread -> row sc_+64i, granule sgj (coalesced 128B/8thr)
    const int sc_ = tid >> 3, sgj = tid & 7;
    const unsigned short* vsrc = vbuf + ((size_t)(b * C_) + sc_) * N_ + sgj * 8;
    const int vdst = (sgj ^ (sc_ & 7)) << 3;         // swizzled granule (const: 64i%8==0)
    // K granules: threads 0..255 -> row kjl, granule kgk
    const int kjl = (tid & 255) >> 2, kgk = tid & 3;
    const unsigned short* ksrc = kT + ((size_t)(b * N_) + kjl) * 32 + kgk * 8;
    const bool do_k = tid < 256;

    f32x16 acc0, acc1, zero16;
#pragma unroll
    for (int r = 0; r < 16; ++r) { acc0[r] = 0.f; acc1[r] = 0.f; zero16[r] = 0.f; }
    float m = -1e30f, l = 0.f;

    // ---- prologue: stage tile 0 into buf 0 ----
    {
        uint4 vr[4];
#pragma unroll
        for (int i = 0; i < 4; ++i)
            vr[i] = *(const uint4*)(vsrc + (size_t)(64 * i) * N_);
        uint4 kr;
        if (do_k) kr = *(const uint4*)(ksrc);
#pragma unroll
        for (int i = 0; i < 4; ++i)
            *(uint4*)&Vl[0][sc_ + 64 * i][vdst] = vr[i];
        if (do_k) *(uint4*)&Kl[0][kjl][kgk * 8] = kr;
    }
    BAR();

    for (int t = 0; t < 64; ++t) {
        const int cu_ = t & 1, nx_ = cu_ ^ 1;

        // ---- issue global loads for tile t+1 (land under QK+softmax) ----
        uint4 vr[4]; uint4 kr;
        if (t < 63) {
            const int jn = (t + 1) * 64;
#pragma unroll
            for (int i = 0; i < 4; ++i)
                vr[i] = *(const uint4*)(vsrc + (size_t)(64 * i) * N_ + jn);
            if (do_k) kr = *(const uint4*)(ksrc + (size_t)jn * 32);
        }

        // ---- QK (swapped): sv[blk] = S[kv][q], kv = 32blk + (r&3)+8(r>>2)+4h ----
        const unsigned short* krow = &Kl[cu_][q][0];
        short8 ka0 = *(const short8*)(krow + 8 * h);
        short8 ka1 = *(const short8*)(krow + 16 + 8 * h);
        short8 ka2 = *(const short8*)(krow + 32 * 40 + 8 * h);
        short8 ka3 = *(const short8*)(krow + 32 * 40 + 16 + 8 * h);
        f32x16 sv0 = __builtin_amdgcn_mfma_f32_32x32x16_bf16(ka0, qf0, zero16, 0, 0, 0);
        sv0 = __builtin_amdgcn_mfma_f32_32x32x16_bf16(ka1, qf1, sv0, 0, 0, 0);
        f32x16 sv1 = __builtin_amdgcn_mfma_f32_32x32x16_bf16(ka2, qf0, zero16, 0, 0, 0);
        sv1 = __builtin_amdgcn_mfma_f32_32x32x16_bf16(ka3, qf1, sv1, 0, 0, 0);

        // ---- online softmax for row q (32 in-lane + partner lane^32) ----
        float t16[16];
#pragma unroll
        for (int r = 0; r < 16; ++r) t16[r] = fmaxf(sv0[r], sv1[r]);
#pragma unroll
        for (int r = 0; r < 8; ++r) t16[r] = fmaxf(t16[r], t16[r + 8]);
#pragma unroll
        for (int r = 0; r < 4; ++r) t16[r] = fmaxf(t16[r], t16[r + 4]);
        float mx = fmaxf(fmaxf(t16[0], t16[1]), fmaxf(t16[2], t16[3]));
        mx = fmaxf(mx, __shfl_xor(mx, 32, 64));
        const float mn = fmaxf(m, mx);
        const float scf = EXP2(m - mn);
        m = mn;
        if (h == 0) scl[wid][q] = scf;

#pragma unroll
        for (int r = 0; r < 16; ++r) { sv0[r] = EXP2(sv0[r] - mn); sv1[r] = EXP2(sv1[r] - mn); }
        float u16[16];
#pragma unroll
        for (int r = 0; r < 16; ++r) u16[r] = sv0[r] + sv1[r];
#pragma unroll
        for (int r = 0; r < 8; ++r) u16[r] += u16[r + 8];
#pragma unroll
        for (int r = 0; r < 4; ++r) u16[r] += u16[r + 4];
        float ps = (u16[0] + u16[1]) + (u16[2] + u16[3]);
        ps += __shfl_xor(ps, 32, 64);
        l = l * scf + ps;

        // ---- write staged tile t+1 (vmcnt satisfied by vr dataflow) ----
        if (t < 63) {
#pragma unroll
            for (int i = 0; i < 4; ++i)
                *(uint4*)&Vl[nx_][sc_ + 64 * i][vdst] = vr[i];
            if (do_k) *(uint4*)&Kl[nx_][kjl][kgk * 8] = kr;
        }

        // ---- pack P quads + lane^32 exchange -> PV A-frags (no LDS) ----
        unsigned int P0[2][4], P1[2][4];
#pragma unroll
        for (int s = 0; s < 4; ++s) {
            P0[0][s] = pack_bf(sv0[4 * s], sv0[4 * s + 1]);
            P1[0][s] = pack_bf(sv0[4 * s + 2], sv0[4 * s + 3]);
            P0[1][s] = pack_bf(sv1[4 * s], sv1[4 * s + 1]);
            P1[1][s] = pack_bf(sv1[4 * s + 2], sv1[4 * s + 3]);
        }
        short8 pa[4];
#pragma unroll
        for (int mm = 0; mm < 4; ++mm) {
            const int blk = mm >> 1, se = 2 * (mm & 1);
            unsigned int e0 = P0[blk][se],     e1 = P1[blk][se];
            unsigned int o0 = P0[blk][se + 1], o1 = P1[blk][se + 1];
            unsigned int s0 = h ? e0 : o0;
            unsigned int s1 = h ? e1 : o1;
            unsigned int r0 = __shfl_xor(s0, 32, 64);
            unsigned int r1 = __shfl_xor(s1, 32, 64);
            frag_u f;
            f.u[0] = h ? r0 : e0;  f.u[1] = h ? r1 : e1;
            f.u[2] = h ? o0 : r0;  f.u[3] = h ? o1 : r1;
            pa[mm] = f.s;
        }

        // ---- guarded rescale (scales via per-wave LDS row) ----
        asm volatile("s_waitcnt lgkmcnt(0)" ::: "memory");
        if (__any(scf != 1.0f)) {
            f32x4 s0 = *(const f32x4*)&scl[wid][4 * h];
            f32x4 s1 = *(const f32x4*)&scl[wid][8 + 4 * h];
            f32x4 s2 = *(const f32x4*)&scl[wid][16 + 4 * h];
            f32x4 s3 = *(const f32x4*)&scl[wid][24 + 4 * h];
#pragma unroll
            for (int r = 0; r < 4; ++r) {
                acc0[r] *= s0[r];      acc1[r] *= s0[r];
                acc0[4 + r] *= s1[r];  acc1[4 + r] *= s1[r];
                acc0[8 + r] *= s2[r];  acc1[8 + r] *= s2[r];
                acc0[12 + r] *= s3[r]; acc1[12 + r] *= s3[r];
            }
        }

        // ---- PV: vf from swizzled LDS; D[q][c] += P[q][kv] V[c][kv] ----
#pragma unroll
        for (int mm = 0; mm < 4; ++mm) {
            const int g = ((2 * mm + h) ^ (q & 7)) << 3;
            short8 vfa = *(const short8*)&Vl[cu_][c0w + q][g];
            short8 vfb = *(const short8*)&Vl[cu_][c0w + 32 + q][g];
            acc0 = __builtin_amdgcn_mfma_f32_32x32x16_bf16(pa[mm], vfa, acc0, 0, 0, 0);
            acc1 = __builtin_amdgcn_mfma_f32_32x32x16_bf16(pa[mm], vfb, acc1, 0, 0, 0);
        }

        BAR();
    }

    // ---- epilogue: out = gamma/l * acc + x ----
    if (h == 0) scl[wid][q] = l;
    asm volatile("s_waitcnt lgkmcnt(0)" ::: "memory");
    const float gm = gamma[0];
    f32x4 lv[4];
    lv[0] = *(const f32x4*)&scl[wid][4 * h];
    lv[1] = *(const f32x4*)&scl[wid][8 + 4 * h];
    lv[2] = *(const f32x4*)&scl[wid][16 + 4 * h];
    lv[3] = *(const f32x4*)&scl[wid][24 + 4 * h];
    float inv[4][4];
#pragma unroll
    for (int s = 0; s < 4; ++s)
#pragma unroll
        for (int r = 0; r < 4; ++r) inv[s][r] = gm / lv[s][r];

#pragma unroll
    for (int cf = 0; cf < 2; ++cf) {
        const int c = c0w + 32 * cf + q;
#pragma unroll
        for (int s = 0; s < 4; ++s) {
            const size_t oidx = ((size_t)(b * C_ + c)) * N_ + iq + 8 * s + 4 * h;
            const float4 xr = *(const float4*)(x + oidx);
            float4 res;
            const float a0 = cf ? acc1[4 * s + 0] : acc0[4 * s + 0];
            const float a1 = cf ? acc1[4 * s + 1] : acc0[4 * s + 1];
            const float a2 = cf ? acc1[4 * s + 2] : acc0[4 * s + 2];
            const float a3 = cf ? acc1[4 * s + 3] : acc0[4 * s + 3];
            res.x = a0 * inv[s][0] + xr.x;
            res.y = a1 * inv[s][1] + xr.y;
            res.z = a2 * inv[s][2] + xr.z;
            res.w = a3 * inv[s][3] + xr.w;
            *(float4*)(out + oidx) = res;
        }
    }
}

extern "C" void kernel_launch(void* const* d_in, const int* in_sizes, int n_in,
                              void* d_out, int out_size, void* d_ws, size_t ws_size,
                              hipStream_t stream) {
    (void)in_sizes; (void)n_in; (void)out_size; (void)ws_size;
    const float* x  = (const float*)d_in[0];
    const float* Wq = (const float*)d_in[1];
    const float* bq = (const float*)d_in[2];
    const float* Wk = (const float*)d_in[3];
    const float* bk = (const float*)d_in[4];
    const float* Wv = (const float*)d_in[5];
    const float* bv = (const float*)d_in[6];
    const float* gm = (const float*)d_in[7];
    float* out = (float*)d_out;

    char* ws = (char*)d_ws;
    unsigned short* wb = (unsigned short*)ws;                                // 160 KB
    float*          bb = (float*)(ws + 320 * 256 * 2);                       // 1.25 KB
    unsigned short* qT = (unsigned short*)(ws + 320 * 256 * 2 + 320 * 4);    // 1 MB
    unsigned short* kT = qT + (size_t)B_ * N_ * 32;                          // 1 MB
    unsigned short* vb = kT + (size_t)B_ * N_ * 32;                          // 8 MB

    hipLaunchKernelGGL(prep_kernel, dim3(320), dim3(64), 0, stream,
                       Wq, bq, Wk, bk, Wv, bv, wb, bb);
    hipLaunchKernelGGL(proj_kernel, dim3(256), dim3(256), 0, stream,
                       x, wb, bb, qT, kT, vb);
    hipLaunchKernelGGL(attn_kernel, dim3(256), dim3(512), 0, stream,
                       qT, kT, vb, x, gm, out);
}

// Round 11
// 109.139 us; speedup vs baseline: 2.5573x; 1.7511x over previous
//
#include <hip/hip_runtime.h>
#include <stdint.h>

#define B_ 4
#define C_ 256
#define N_ 4096
#define LOG2E 1.44269504088896341f
#define EXP2(x) __builtin_amdgcn_exp2f(x)

typedef __attribute__((ext_vector_type(8))) short short8;
typedef __attribute__((ext_vector_type(4))) float f32x4;

__device__ __forceinline__ unsigned short f2bf(float f) {
    unsigned int u = __float_as_uint(f);
    u += 0x7FFFu + ((u >> 16) & 1u);
    return (unsigned short)(u >> 16);
}

// pack two f32 -> 2 bf16 in one u32 (round-half-up)
__device__ __forceinline__ unsigned int pack_bf(float a, float b) {
    unsigned int ua = __float_as_uint(a) + 0x8000u;
    unsigned int ub = __float_as_uint(b) + 0x8000u;
    return __builtin_amdgcn_perm(ub, ua, 0x07060302u);  // [b_hi16 | a_hi16]
}
__device__ __forceinline__ float bf_lo(unsigned int u) { return __uint_as_float(u << 16); }
__device__ __forceinline__ float bf_hi(unsigned int u) { return __uint_as_float(u & 0xFFFF0000u); }

// ---------------------------------------------------------------------------
// prep: pack W -> wb[320][256] bf16 (rows 0-31 Wq*(log2e/16), 32-63 Wk, 64-319 Wv)
// ---------------------------------------------------------------------------
__global__ __launch_bounds__(64) void prep_kernel(
    const float* __restrict__ Wq, const float* __restrict__ bq,
    const float* __restrict__ Wk, const float* __restrict__ bk,
    const float* __restrict__ Wv, const float* __restrict__ bv,
    unsigned short* __restrict__ wb, float* __restrict__ bb)
{
    const int m = blockIdx.x;
    const int t = threadIdx.x;
    const float* src;
    float scale = 1.0f, bias;
    if (m < 32)      { src = Wq + m * C_;        scale = 0.0625f * LOG2E; bias = bq[m] * 0.0625f * LOG2E; }
    else if (m < 64) { src = Wk + (m - 32) * C_;                          bias = bk[m - 32]; }
    else             { src = Wv + (m - 64) * C_;                          bias = bv[m - 64]; }
    float4 v = *(const float4*)(src + t * 4);
    unsigned int lo = (unsigned int)f2bf(v.x * scale) | ((unsigned int)f2bf(v.y * scale) << 16);
    unsigned int hi = (unsigned int)f2bf(v.z * scale) | ((unsigned int)f2bf(v.w * scale) << 16);
    *(uint2*)(wb + m * C_ + t * 4) = make_uint2(lo, hi);
    if (t == 0) bb[m] = bias;
}

// ---------------------------------------------------------------------------
// proj (MFMA GEMM): D[m][n] = sum_k wb[m][k] * x[b][k][n]  (+bias)
// ---------------------------------------------------------------------------
__global__ __launch_bounds__(256) void proj_kernel(
    const float* __restrict__ x,
    const unsigned short* __restrict__ wb, const float* __restrict__ bb,
    unsigned short* __restrict__ qT, unsigned short* __restrict__ kT,
    unsigned short* __restrict__ vb)
{
    __shared__ unsigned short xs[256][68];

    const int bid = ((blockIdx.x & 7) << 5) + (blockIdx.x >> 3);
    const int b = bid >> 6, n0 = (bid & 63) << 6;
    const int tid = threadIdx.x, wid = tid >> 6, lane = tid & 63;
    const int l15 = lane & 15, l4 = lane >> 4;

#pragma unroll
    for (int it = 0; it < 16; ++it) {
        int idx = it * 256 + tid;
        int k = idx >> 4, n4 = (idx & 15) << 2;
        float4 v = *(const float4*)(x + ((size_t)(b * C_ + k)) * N_ + n0 + n4);
        unsigned int lo = (unsigned int)f2bf(v.x) | ((unsigned int)f2bf(v.y) << 16);
        unsigned int hi = (unsigned int)f2bf(v.z) | ((unsigned int)f2bf(v.w) << 16);
        *(uint2*)&xs[k][n4] = make_uint2(lo, hi);
    }
    __syncthreads();

    const int m0 = wid * 80;
    f32x4 acc[5][4];
#pragma unroll
    for (int mf = 0; mf < 5; ++mf)
#pragma unroll
        for (int nt = 0; nt < 4; ++nt)
            acc[mf][nt] = (f32x4){0.f, 0.f, 0.f, 0.f};

#pragma unroll
    for (int s = 0; s < 8; ++s) {
        short8 wf[5];
#pragma unroll
        for (int mf = 0; mf < 5; ++mf)
            wf[mf] = *(const short8*)(wb + (size_t)(m0 + 16 * mf + l15) * C_ + 32 * s + 8 * l4);
        short8 xf[4];
#pragma unroll
        for (int nt = 0; nt < 4; ++nt) {
#pragma unroll
            for (int e = 0; e < 8; ++e)
                xf[nt][e] = (short)xs[32 * s + 8 * l4 + e][16 * nt + l15];
        }
#pragma unroll
        for (int mf = 0; mf < 5; ++mf)
#pragma unroll
            for (int nt = 0; nt < 4; ++nt)
                acc[mf][nt] = __builtin_amdgcn_mfma_f32_16x16x32_bf16(wf[mf], xf[nt], acc[mf][nt], 0, 0, 0);
    }

#pragma unroll
    for (int mf = 0; mf < 5; ++mf) {
        const int mbase = m0 + 16 * mf + 4 * l4;
        const float4 b4 = *(const float4*)(bb + mbase);
        const int region = (m0 + 16 * mf) >> 5;
#pragma unroll
        for (int nt = 0; nt < 4; ++nt) {
            const int n = n0 + 16 * nt + l15;
            float o0 = acc[mf][nt][0] + b4.x;
            float o1 = acc[mf][nt][1] + b4.y;
            float o2 = acc[mf][nt][2] + b4.z;
            float o3 = acc[mf][nt][3] + b4.w;
            if (region == 0) {
                *(uint2*)(qT + ((size_t)(b * N_ + n)) * 32 + mbase) =
                    make_uint2(pack_bf(o0, o1), pack_bf(o2, o3));
            } else if (region == 1) {
                *(uint2*)(kT + ((size_t)(b * N_ + n)) * 32 + (mbase - 32)) =
                    make_uint2(pack_bf(o0, o1), pack_bf(o2, o3));
            } else {
                const int c = mbase - 64;
                vb[((size_t)(b * C_ + c + 0)) * N_ + n] = f2bf(o0);
                vb[((size_t)(b * C_ + c + 1)) * N_ + n] = f2bf(o1);
                vb[((size_t)(b * C_ + c + 2)) * N_ + n] = f2bf(o2);
                vb[((size_t)(b * C_ + c + 3)) * N_ + n] = f2bf(o3);
            }
        }
    }
}

// ---------------------------------------------------------------------------
// attn_part: r4's producer-consumer flash attention over HALF the KV range.
// grid 512 = (b, q-tile of 64, kv-half); 512 threads = 8 waves.
// waves 0-3 (QK): swapped QK^T + online softmax (native exp2); publish P+scale.
// waves 4-7 (PV): consume P(t-1), V direct from L2 (reg ping-pong).
// Epilogue: dump unnormalized O_part (bf16) + per-row (m,l) to workspace.
// 2 independent blocks/CU -> 16 waves/CU, cross-block latency hiding.
// ---------------------------------------------------------------------------
__global__ __launch_bounds__(512, 2) void attn_part_kernel(
    const unsigned short* __restrict__ qT, const unsigned short* __restrict__ kT,
    const unsigned short* __restrict__ vbuf,
    unsigned short* __restrict__ po, float* __restrict__ mlb)
{
    __shared__ unsigned short Pl[2][64][72];   // [buf][q][j] bf16
    __shared__ float sc_l[2][64];              // [buf][q] rescale factors

    const int raw = blockIdx.x;
    const int bid = ((raw & 7) << 6) | (raw >> 3);   // XCD r: 64 consecutive bids
    const int b = bid >> 7;
    const int qt = (bid >> 1) & 63;
    const int s = bid & 1;
    const int i0 = qt << 6;
    const int j0 = s << 11;                          // kv offset: 0 or 2048
    const int tid = threadIdx.x, wid = tid >> 6, lane = tid & 63;
    const int l15 = lane & 15, l4 = lane >> 4;
    const f32x4 zero = {0.f, 0.f, 0.f, 0.f};

    if (wid < 4) {
        // ================= QK / softmax producer =================
        const short8 qfrag = *(const short8*)(
            qT + ((size_t)(b * N_ + i0 + 16 * wid + l15)) * 32 + 8 * l4);
        const unsigned short* kbase = kT + ((size_t)(b * N_ + j0) + l15) * 32 + 8 * l4;

        short8 ka[4], kb_[4];
        _Pragma("unroll")
        for (int f = 0; f < 4; ++f)
            ka[f] = *(const short8*)(kbase + (size_t)(16 * f) * 32);

        float m = -1e30f, l = 0.f;

#define QK_BODY(T, KC, KN)                                                        \
  {                                                                               \
    if ((T) < 31) {                                                               \
      _Pragma("unroll")                                                           \
      for (int f = 0; f < 4; ++f)                                                 \
        KN[f] = *(const short8*)(kbase + (size_t)(((T) + 1) * 64 + 16 * f) * 32); \
    }                                                                             \
    f32x4 sv[4];                                                                  \
    _Pragma("unroll")                                                             \
    for (int f = 0; f < 4; ++f)                                                   \
      sv[f] = __builtin_amdgcn_mfma_f32_16x16x32_bf16(KC[f], qfrag, zero, 0, 0, 0);\
    float m4[4];                                                                  \
    _Pragma("unroll")                                                             \
    for (int f = 0; f < 4; ++f)                                                   \
      m4[f] = fmaxf(fmaxf(sv[f][0], sv[f][1]), fmaxf(sv[f][2], sv[f][3]));        \
    float mx = fmaxf(fmaxf(m4[0], m4[1]), fmaxf(m4[2], m4[3]));                   \
    mx = fmaxf(mx, __shfl_xor(mx, 16, 64));                                       \
    mx = fmaxf(mx, __shfl_xor(mx, 32, 64));                                       \
    const float mn = fmaxf(m, mx);                                                \
    const float scf = EXP2(m - mn);                                               \
    m = mn;                                                                       \
    float ps = 0.f;                                                               \
    _Pragma("unroll")                                                             \
    for (int f = 0; f < 4; ++f) {                                                 \
      _Pragma("unroll")                                                           \
      for (int r = 0; r < 4; ++r) { sv[f][r] = EXP2(sv[f][r] - mn); ps += sv[f][r]; } \
    }                                                                             \
    ps += __shfl_xor(ps, 16, 64);                                                 \
    ps += __shfl_xor(ps, 32, 64);                                                 \
    l = l * scf + ps;                                                             \
    unsigned short* prow = &Pl[(T) & 1][16 * wid + l15][4 * l4];                  \
    _Pragma("unroll")                                                             \
    for (int f = 0; f < 4; ++f)                                                   \
      *(uint2*)(prow + 16 * f) = make_uint2(pack_bf(sv[f][0], sv[f][1]),          \
                                            pack_bf(sv[f][2], sv[f][3]));         \
    if (l4 == 0) sc_l[(T) & 1][16 * wid + l15] = scf;                             \
  }

        for (int u = 0; u < 16; ++u) {
            QK_BODY(2 * u, ka, kb_)
            __syncthreads();
            QK_BODY(2 * u + 1, kb_, ka)
            __syncthreads();
        }
        if (l4 == 0) {
            mlb[(size_t)bid * 128 + 16 * wid + l15] = m;
            mlb[(size_t)bid * 128 + 64 + 16 * wid + l15] = l;
        }
        __syncthreads();
        // QK waves exit
    } else {
        // ================= PV consumer =================
        const int c0 = (wid - 4) << 6;
        const unsigned short* vrow[4];
        _Pragma("unroll")
        for (int nb = 0; nb < 4; ++nb)
            vrow[nb] = vbuf + ((size_t)(b * C_ + c0 + 16 * nb + l15)) * N_ + j0 + 8 * l4;

        f32x4 acc[4][4];
        _Pragma("unroll")
        for (int qf = 0; qf < 4; ++qf) {
            _Pragma("unroll")
            for (int nb = 0; nb < 4; ++nb)
                acc[qf][nb] = (f32x4){0.f, 0.f, 0.f, 0.f};
        }

        short8 va_[4][2], vb2_[4][2];

#define PV_LOAD(DST, T)                                                           \
    {                                                                             \
      _Pragma("unroll")                                                           \
      for (int nb = 0; nb < 4; ++nb) {                                            \
        _Pragma("unroll")                                                         \
        for (int kb = 0; kb < 2; ++kb)                                            \
          DST[nb][kb] = *(const short8*)(vrow[nb] + (T) * 64 + kb * 32);          \
      }                                                                           \
    }

#define PV_BODY(T, VC, VN)                                                        \
  {                                                                               \
    if ((T) >= 1 && (T) < 32) PV_LOAD(VN, (T))                                    \
    const int bf = ((T) + 1) & 1; /* == (T-1)&1 */                                \
    short8 pa[4][2];                                                              \
    _Pragma("unroll")                                                             \
    for (int qf = 0; qf < 4; ++qf) {                                              \
      _Pragma("unroll")                                                           \
      for (int kb = 0; kb < 2; ++kb)                                              \
        pa[qf][kb] = *(const short8*)&Pl[bf][16 * qf + l15][kb * 32 + 8 * l4];    \
    }                                                                             \
    f32x4 scv_[4];                                                                \
    bool need = false;                                                            \
    _Pragma("unroll")                                                             \
    for (int qf = 0; qf < 4; ++qf) {                                              \
      scv_[qf] = *(const f32x4*)&sc_l[bf][16 * qf + 4 * l4];                      \
      _Pragma("unroll")                                                           \
      for (int r = 0; r < 4; ++r) need = need || (scv_[qf][r] != 1.0f);           \
    }                                                                             \
    if (__any(need)) {                                                            \
      _Pragma("unroll")                                                           \
      for (int qf = 0; qf < 4; ++qf) {                                            \
        _Pragma("unroll")                                                         \
        for (int nb = 0; nb < 4; ++nb) {                                          \
          _Pragma("unroll")                                                       \
          for (int r = 0; r < 4; ++r) acc[qf][nb][r] *= scv_[qf][r];              \
        }                                                                         \
      }                                                                           \
    }                                                                             \
    __builtin_amdgcn_s_setprio(1);                                                \
    _Pragma("unroll")                                                             \
    for (int qf = 0; qf < 4; ++qf) {                                              \
      _Pragma("unroll")                                                           \
      for (int kb = 0; kb < 2; ++kb) {                                            \
        _Pragma("unroll")                                                         \
        for (int nb = 0; nb < 4; ++nb)                                            \
          acc[qf][nb] = __builtin_amdgcn_mfma_f32_16x16x32_bf16(pa[qf][kb], VC[nb][kb], acc[qf][nb], 0, 0, 0); \
      }                                                                           \
    }                                                                             \
    __builtin_amdgcn_s_setprio(0);                                                \
  }

        PV_LOAD(vb2_, 0)          // prologue: tile 0
        __syncthreads();          // matches QK's barrier after body 0
        for (int u = 0; u < 16; ++u) {
            PV_BODY(2 * u + 1, vb2_, va_)
            __syncthreads();
            PV_BODY(2 * u + 2, va_, vb2_)
            __syncthreads();
        }

        // epilogue: dump unnormalized partial O as bf16
        unsigned short* pbase = po + ((size_t)bid << 14);   // 16384 ush per block
        _Pragma("unroll")
        for (int qf = 0; qf < 4; ++qf) {
            _Pragma("unroll")
            for (int nb = 0; nb < 4; ++nb) {
                const int c = c0 + 16 * nb + l15;
                *(uint2*)(pbase + c * 64 + 16 * qf + 4 * l4) =
                    make_uint2(pack_bf(acc[qf][nb][0], acc[qf][nb][1]),
                               pack_bf(acc[qf][nb][2], acc[qf][nb][3]));
            }
        }
    }
}

// ---------------------------------------------------------------------------
// reduce: combine 2 KV-half partials, normalize, apply gamma and residual.
// grid 1024 = (b*64+qt)*4 + c-quarter; 256 threads (i4 fast x 16 channels).
// out[c][i] = gamma * (O0*w0 + O1*w1) / (l0*w0 + l1*w1) + x,  w_s = exp2(m_s - m*)
// ---------------------------------------------------------------------------
__global__ __launch_bounds__(256) void reduce_kernel(
    const unsigned short* __restrict__ po, const float* __restrict__ mlb,
    const float* __restrict__ x, const float* __restrict__ gamma,
    float* __restrict__ out)
{
    __shared__ float a0l[64], a1l[64];

    const int bq = blockIdx.x >> 2;           // b*64 + qt
    const int cq = blockIdx.x & 3;
    const int b = bq >> 6, qt = bq & 63;
    const int lid0 = bq << 1, lid1 = lid0 | 1;
    const int tid = threadIdx.x;

    if (tid < 64) {
        const float m0 = mlb[(size_t)lid0 * 128 + tid];
        const float l0 = mlb[(size_t)lid0 * 128 + 64 + tid];
        const float m1 = mlb[(size_t)lid1 * 128 + tid];
        const float l1 = mlb[(size_t)lid1 * 128 + 64 + tid];
        const float ms = fmaxf(m0, m1);
        const float w0 = EXP2(m0 - ms), w1 = EXP2(m1 - ms);
        const float inv = gamma[0] / (l0 * w0 + l1 * w1);
        a0l[tid] = w0 * inv;
        a1l[tid] = w1 * inv;
    }
    __syncthreads();

    const int i4 = tid & 15, c16 = tid >> 4;
    const float4 av0 = *(const float4*)&a0l[i4 * 4];
    const float4 av1 = *(const float4*)&a1l[i4 * 4];

#pragma unroll
    for (int cc = 0; cc < 4; ++cc) {
        const int c = (cq << 6) + cc * 16 + c16;
        const uint2 p0 = *(const uint2*)(po + ((size_t)lid0 << 14) + c * 64 + i4 * 4);
        const uint2 p1 = *(const uint2*)(po + ((size_t)lid1 << 14) + c * 64 + i4 * 4);
        const size_t xi = ((size_t)(b * C_ + c)) * N_ + (qt << 6) + i4 * 4;
        const float4 xr = *(const float4*)(x + xi);
        float4 res;
        res.x = bf_lo(p0.x) * av0.x + bf_lo(p1.x) * av1.x + xr.x;
        res.y = bf_hi(p0.x) * av0.y + bf_hi(p1.x) * av1.y + xr.y;
        res.z = bf_lo(p0.y) * av0.z + bf_lo(p1.y) * av1.z + xr.z;
        res.w = bf_hi(p0.y) * av0.w + bf_hi(p1.y) * av1.w + xr.w;
        *(float4*)(out + xi) = res;
    }
}

extern "C" void kernel_launch(void* const* d_in, const int* in_sizes, int n_in,
                              void* d_out, int out_size, void* d_ws, size_t ws_size,
                              hipStream_t stream) {
    (void)in_sizes; (void)n_in; (void)out_size; (void)ws_size;
    const float* x  = (const float*)d_in[0];
    const float* Wq = (const float*)d_in[1];
    const float* bq = (const float*)d_in[2];
    const float* Wk = (const float*)d_in[3];
    const float* bk = (const float*)d_in[4];
    const float* Wv = (const float*)d_in[5];
    const float* bv = (const float*)d_in[6];
    const float* gm = (const float*)d_in[7];
    float* out = (float*)d_out;

    char* ws = (char*)d_ws;
    unsigned short* wb = (unsigned short*)ws;                                // 160 KB
    float*          bb = (float*)(ws + 320 * 256 * 2);                       // 1.25 KB
    unsigned short* qT = (unsigned short*)(ws + 320 * 256 * 2 + 320 * 4);    // 1 MB
    unsigned short* kT = qT + (size_t)B_ * N_ * 32;                          // 1 MB
    unsigned short* vb = kT + (size_t)B_ * N_ * 32;                          // 8 MB
    unsigned short* po = vb + (size_t)B_ * C_ * N_;                          // 16 MB (512 x 16384 bf16)
    float*         mlb = (float*)(po + (size_t)512 * 16384);                 // 256 KB

    hipLaunchKernelGGL(prep_kernel, dim3(320), dim3(64), 0, stream,
                       Wq, bq, Wk, bk, Wv, bv, wb, bb);
    hipLaunchKernelGGL(proj_kernel, dim3(256), dim3(256), 0, stream,
                       x, wb, bb, qT, kT, vb);
    hipLaunchKernelGGL(attn_part_kernel, dim3(512), dim3(512), 0, stream,
                       qT, kT, vb, po, mlb);
    hipLaunchKernelGGL(reduce_kernel, dim3(1024), dim3(256), 0, stream,
                       po, mlb, x, gm, out);
}

// Round 12
// 94.531 us; speedup vs baseline: 2.9525x; 1.1545x over previous
//
#include <hip/hip_runtime.h>
#include <stdint.h>

#define B_ 4
#define C_ 256
#define N_ 4096
#define LOG2E 1.44269504088896341f
#define EXP2(x) __builtin_amdgcn_exp2f(x)

typedef __attribute__((ext_vector_type(8))) short short8;
typedef __attribute__((ext_vector_type(4))) float f32x4;

__device__ __forceinline__ unsigned short f2bf(float f) {
    unsigned int u = __float_as_uint(f);
    u += 0x7FFFu + ((u >> 16) & 1u);
    return (unsigned short)(u >> 16);
}

// pack two f32 -> 2 bf16 in one u32 (round-half-up)
__device__ __forceinline__ unsigned int pack_bf(float a, float b) {
    unsigned int ua = __float_as_uint(a) + 0x8000u;
    unsigned int ub = __float_as_uint(b) + 0x8000u;
    return __builtin_amdgcn_perm(ub, ua, 0x07060302u);  // [b_hi16 | a_hi16]
}
__device__ __forceinline__ float bf_lo(unsigned int u) { return __uint_as_float(u << 16); }
__device__ __forceinline__ float bf_hi(unsigned int u) { return __uint_as_float(u & 0xFFFF0000u); }

// ---------------------------------------------------------------------------
// prep: pack W -> wb[320][256] bf16 (rows 0-31 Wq*(log2e/16), 32-63 Wk, 64-319 Wv)
// ---------------------------------------------------------------------------
__global__ __launch_bounds__(64) void prep_kernel(
    const float* __restrict__ Wq, const float* __restrict__ bq,
    const float* __restrict__ Wk, const float* __restrict__ bk,
    const float* __restrict__ Wv, const float* __restrict__ bv,
    unsigned short* __restrict__ wb, float* __restrict__ bb)
{
    const int m = blockIdx.x;
    const int t = threadIdx.x;
    const float* src;
    float scale = 1.0f, bias;
    if (m < 32)      { src = Wq + m * C_;        scale = 0.0625f * LOG2E; bias = bq[m] * 0.0625f * LOG2E; }
    else if (m < 64) { src = Wk + (m - 32) * C_;                          bias = bk[m - 32]; }
    else             { src = Wv + (m - 64) * C_;                          bias = bv[m - 64]; }
    float4 v = *(const float4*)(src + t * 4);
    unsigned int lo = (unsigned int)f2bf(v.x * scale) | ((unsigned int)f2bf(v.y * scale) << 16);
    unsigned int hi = (unsigned int)f2bf(v.z * scale) | ((unsigned int)f2bf(v.w * scale) << 16);
    *(uint2*)(wb + m * C_ + t * 4) = make_uint2(lo, hi);
    if (t == 0) bb[m] = bias;
}

// ---------------------------------------------------------------------------
// proj (MFMA GEMM): D[m][n] = sum_k wb[m][k] * x[b][k][n]  (+bias)
// q,k -> (B,N,32) row layout.  V -> FRAGMENT-MAJOR layout:
//   vfrag[(b*64+jt)*16384 + cblk*1024 + kb*512 + l4*128 + c15*8 + e]
//   (jt = n-tile of 64, cblk = c>>4, kb = (kv&63)>>5, l4 = (kv>>3)&3, e = kv&7)
// so attn's PV B-frag load is one contiguous 2KB wave segment.
// ---------------------------------------------------------------------------
__global__ __launch_bounds__(256) void proj_kernel(
    const float* __restrict__ x,
    const unsigned short* __restrict__ wb, const float* __restrict__ bb,
    unsigned short* __restrict__ qT, unsigned short* __restrict__ kT,
    unsigned short* __restrict__ vfrag)
{
    __shared__ unsigned short xs[256][68];   // x-tile; reused as V-tile after MFMA

    const int bid = ((blockIdx.x & 7) << 5) + (blockIdx.x >> 3);
    const int b = bid >> 6, n0 = (bid & 63) << 6;
    const int tid = threadIdx.x, wid = tid >> 6, lane = tid & 63;
    const int l15 = lane & 15, l4 = lane >> 4;

#pragma unroll
    for (int it = 0; it < 16; ++it) {
        int idx = it * 256 + tid;
        int k = idx >> 4, n4 = (idx & 15) << 2;
        float4 v = *(const float4*)(x + ((size_t)(b * C_ + k)) * N_ + n0 + n4);
        unsigned int lo = (unsigned int)f2bf(v.x) | ((unsigned int)f2bf(v.y) << 16);
        unsigned int hi = (unsigned int)f2bf(v.z) | ((unsigned int)f2bf(v.w) << 16);
        *(uint2*)&xs[k][n4] = make_uint2(lo, hi);
    }
    __syncthreads();

    const int m0 = wid * 80;
    f32x4 acc[5][4];
#pragma unroll
    for (int mf = 0; mf < 5; ++mf)
#pragma unroll
        for (int nt = 0; nt < 4; ++nt)
            acc[mf][nt] = (f32x4){0.f, 0.f, 0.f, 0.f};

#pragma unroll
    for (int s = 0; s < 8; ++s) {
        short8 wf[5];
#pragma unroll
        for (int mf = 0; mf < 5; ++mf)
            wf[mf] = *(const short8*)(wb + (size_t)(m0 + 16 * mf + l15) * C_ + 32 * s + 8 * l4);
        short8 xf[4];
#pragma unroll
        for (int nt = 0; nt < 4; ++nt) {
#pragma unroll
            for (int e = 0; e < 8; ++e)
                xf[nt][e] = (short)xs[32 * s + 8 * l4 + e][16 * nt + l15];
        }
#pragma unroll
        for (int mf = 0; mf < 5; ++mf)
#pragma unroll
            for (int nt = 0; nt < 4; ++nt)
                acc[mf][nt] = __builtin_amdgcn_mfma_f32_16x16x32_bf16(wf[mf], xf[nt], acc[mf][nt], 0, 0, 0);
    }

    __syncthreads();   // all xs reads done; xs becomes the V-tile buffer [c][n_local]

#pragma unroll
    for (int mf = 0; mf < 5; ++mf) {
        const int mbase = m0 + 16 * mf + 4 * l4;
        const float4 b4 = *(const float4*)(bb + mbase);
        const int region = (m0 + 16 * mf) >> 5;
#pragma unroll
        for (int nt = 0; nt < 4; ++nt) {
            const int n = n0 + 16 * nt + l15;
            float o0 = acc[mf][nt][0] + b4.x;
            float o1 = acc[mf][nt][1] + b4.y;
            float o2 = acc[mf][nt][2] + b4.z;
            float o3 = acc[mf][nt][3] + b4.w;
            if (region == 0) {
                *(uint2*)(qT + ((size_t)(b * N_ + n)) * 32 + mbase) =
                    make_uint2(pack_bf(o0, o1), pack_bf(o2, o3));
            } else if (region == 1) {
                *(uint2*)(kT + ((size_t)(b * N_ + n)) * 32 + (mbase - 32)) =
                    make_uint2(pack_bf(o0, o1), pack_bf(o2, o3));
            } else {
                const int c = mbase - 64;
                const int nl = 16 * nt + l15;
                xs[c + 0][nl] = f2bf(o0);
                xs[c + 1][nl] = f2bf(o1);
                xs[c + 2][nl] = f2bf(o2);
                xs[c + 3][nl] = f2bf(o3);
            }
        }
    }

    __syncthreads();   // V-tile complete in LDS

    // fragment-order restage: 2048 fragments of 16B, coalesced global stores
    unsigned short* vout = vfrag + (((size_t)(b * 64 + (n0 >> 6))) << 14);
#pragma unroll
    for (int i = 0; i < 8; ++i) {
        const int fid = i * 256 + tid;
        const int c15 = fid & 15, fl4 = (fid >> 4) & 3, kb = (fid >> 6) & 1, cblk = (fid >> 7) & 15;
        short8 v = *(const short8*)&xs[cblk * 16 + c15][kb * 32 + fl4 * 8];
        *(short8*)(vout + (size_t)fid * 8) = v;
    }
}

// ---------------------------------------------------------------------------
// attn_part: producer-consumer flash attention over HALF the KV range.
// grid 512 = (b, q-tile of 64, kv-half); 512 threads = 8 waves.
// waves 0-3 (QK): swapped QK^T + online softmax; publish P+scale (dbuf LDS).
// waves 4-7 (PV): consume P(t-1); V-frags via COALESCED fragment-layout loads.
// Epilogue: dump unnormalized O_part (bf16) + per-row (m,l).
// ---------------------------------------------------------------------------
__global__ __launch_bounds__(512, 2) void attn_part_kernel(
    const unsigned short* __restrict__ qT, const unsigned short* __restrict__ kT,
    const unsigned short* __restrict__ vfrag,
    unsigned short* __restrict__ po, float* __restrict__ mlb)
{
    __shared__ unsigned short Pl[2][64][72];   // [buf][q][j] bf16
    __shared__ float sc_l[2][64];              // [buf][q] rescale factors

    const int raw = blockIdx.x;
    const int bid = ((raw & 7) << 6) | (raw >> 3);   // XCD r: 64 consecutive bids
    const int b = bid >> 7;
    const int qt = (bid >> 1) & 63;
    const int s = bid & 1;
    const int i0 = qt << 6;
    const int j0 = s << 11;                          // kv offset: 0 or 2048
    const int tid = threadIdx.x, wid = tid >> 6, lane = tid & 63;
    const int l15 = lane & 15, l4 = lane >> 4;
    const f32x4 zero = {0.f, 0.f, 0.f, 0.f};

    if (wid < 4) {
        // ================= QK / softmax producer =================
        const short8 qfrag = *(const short8*)(
            qT + ((size_t)(b * N_ + i0 + 16 * wid + l15)) * 32 + 8 * l4);
        const unsigned short* kbase = kT + ((size_t)(b * N_ + j0) + l15) * 32 + 8 * l4;

        short8 ka[4], kb_[4];
        _Pragma("unroll")
        for (int f = 0; f < 4; ++f)
            ka[f] = *(const short8*)(kbase + (size_t)(16 * f) * 32);

        float m = -1e30f, l = 0.f;

#define QK_BODY(T, KC, KN)                                                        \
  {                                                                               \
    if ((T) < 31) {                                                               \
      _Pragma("unroll")                                                           \
      for (int f = 0; f < 4; ++f)                                                 \
        KN[f] = *(const short8*)(kbase + (size_t)(((T) + 1) * 64 + 16 * f) * 32); \
    }                                                                             \
    f32x4 sv[4];                                                                  \
    _Pragma("unroll")                                                             \
    for (int f = 0; f < 4; ++f)                                                   \
      sv[f] = __builtin_amdgcn_mfma_f32_16x16x32_bf16(KC[f], qfrag, zero, 0, 0, 0);\
    float m4[4];                                                                  \
    _Pragma("unroll")                                                             \
    for (int f = 0; f < 4; ++f)                                                   \
      m4[f] = fmaxf(fmaxf(sv[f][0], sv[f][1]), fmaxf(sv[f][2], sv[f][3]));        \
    float mx = fmaxf(fmaxf(m4[0], m4[1]), fmaxf(m4[2], m4[3]));                   \
    mx = fmaxf(mx, __shfl_xor(mx, 16, 64));                                       \
    mx = fmaxf(mx, __shfl_xor(mx, 32, 64));                                       \
    const float mn = fmaxf(m, mx);                                                \
    const float scf = EXP2(m - mn);                                               \
    m = mn;                                                                       \
    float ps = 0.f;                                                               \
    _Pragma("unroll")                                                             \
    for (int f = 0; f < 4; ++f) {                                                 \
      _Pragma("unroll")                                                           \
      for (int r = 0; r < 4; ++r) { sv[f][r] = EXP2(sv[f][r] - mn); ps += sv[f][r]; } \
    }                                                                             \
    ps += __shfl_xor(ps, 16, 64);                                                 \
    ps += __shfl_xor(ps, 32, 64);                                                 \
    l = l * scf + ps;                                                             \
    unsigned short* prow = &Pl[(T) & 1][16 * wid + l15][4 * l4];                  \
    _Pragma("unroll")                                                             \
    for (int f = 0; f < 4; ++f)                                                   \
      *(uint2*)(prow + 16 * f) = make_uint2(pack_bf(sv[f][0], sv[f][1]),          \
                                            pack_bf(sv[f][2], sv[f][3]));         \
    if (l4 == 0) sc_l[(T) & 1][16 * wid + l15] = scf;                             \
  }

        for (int u = 0; u < 16; ++u) {
            QK_BODY(2 * u, ka, kb_)
            __syncthreads();
            QK_BODY(2 * u + 1, kb_, ka)
            __syncthreads();
        }
        if (l4 == 0) {
            mlb[(size_t)bid * 128 + 16 * wid + l15] = m;
            mlb[(size_t)bid * 128 + 64 + 16 * wid + l15] = l;
        }
        __syncthreads();
        // QK waves exit
    } else {
        // ================= PV consumer =================
        const int c0 = (wid - 4) << 6;
        // fragment-layout base: tile jt = s*32+T ; frag offset cblk*1024+kb*512+l4*128+l15*8
        const unsigned short* vfb_ = vfrag + (((size_t)(b * 64 + s * 32)) << 14)
                                   + ((size_t)(c0 >> 4) << 10) + l4 * 128 + l15 * 8;

        f32x4 acc[4][4];
        _Pragma("unroll")
        for (int qf = 0; qf < 4; ++qf) {
            _Pragma("unroll")
            for (int nb = 0; nb < 4; ++nb)
                acc[qf][nb] = (f32x4){0.f, 0.f, 0.f, 0.f};
        }

        short8 va_[4][2], vb2_[4][2];

#define PV_LOAD(DST, T)                                                           \
    {                                                                             \
      _Pragma("unroll")                                                           \
      for (int nb = 0; nb < 4; ++nb) {                                            \
        _Pragma("unroll")                                                         \
        for (int kb = 0; kb < 2; ++kb)                                            \
          DST[nb][kb] = *(const short8*)(vfb_ + ((size_t)(T) << 14) + nb * 1024 + kb * 512); \
      }                                                                           \
    }

#define PV_BODY(T, VC, VN)                                                        \
  {                                                                               \
    if ((T) >= 1 && (T) < 32) PV_LOAD(VN, (T))                                    \
    const int bf = ((T) + 1) & 1; /* == (T-1)&1 */                                \
    short8 pa[4][2];                                                              \
    _Pragma("unroll")                                                             \
    for (int qf = 0; qf < 4; ++qf) {                                              \
      _Pragma("unroll")                                                           \
      for (int kb = 0; kb < 2; ++kb)                                              \
        pa[qf][kb] = *(const short8*)&Pl[bf][16 * qf + l15][kb * 32 + 8 * l4];    \
    }                                                                             \
    f32x4 scv_[4];                                                                \
    bool need = false;                                                            \
    _Pragma("unroll")                                                             \
    for (int qf = 0; qf < 4; ++qf) {                                              \
      scv_[qf] = *(const f32x4*)&sc_l[bf][16 * qf + 4 * l4];                      \
      _Pragma("unroll")                                                           \
      for (int r = 0; r < 4; ++r) need = need || (scv_[qf][r] != 1.0f);           \
    }                                                                             \
    if (__any(need)) {                                                            \
      _Pragma("unroll")                                                           \
      for (int qf = 0; qf < 4; ++qf) {                                            \
        _Pragma("unroll")                                                         \
        for (int nb = 0; nb < 4; ++nb) {                                          \
          _Pragma("unroll")                                                       \
          for (int r = 0; r < 4; ++r) acc[qf][nb][r] *= scv_[qf][r];              \
        }                                                                         \
      }                                                                           \
    }                                                                             \
    __builtin_amdgcn_s_setprio(1);                                                \
    _Pragma("unroll")                                                             \
    for (int qf = 0; qf < 4; ++qf) {                                              \
      _Pragma("unroll")                                                           \
      for (int kb = 0; kb < 2; ++kb) {                                            \
        _Pragma("unroll")                                                         \
        for (int nb = 0; nb < 4; ++nb)                                            \
          acc[qf][nb] = __builtin_amdgcn_mfma_f32_16x16x32_bf16(pa[qf][kb], VC[nb][kb], acc[qf][nb], 0, 0, 0); \
      }                                                                           \
    }                                                                             \
    __builtin_amdgcn_s_setprio(0);                                                \
  }

        PV_LOAD(vb2_, 0)          // prologue: tile 0
        __syncthreads();          // matches QK's barrier after body 0
        for (int u = 0; u < 16; ++u) {
            PV_BODY(2 * u + 1, vb2_, va_)
            __syncthreads();
            PV_BODY(2 * u + 2, va_, vb2_)
            __syncthreads();
        }

        // epilogue: dump unnormalized partial O as bf16
        unsigned short* pbase = po + ((size_t)bid << 14);   // 16384 ush per block
        _Pragma("unroll")
        for (int qf = 0; qf < 4; ++qf) {
            _Pragma("unroll")
            for (int nb = 0; nb < 4; ++nb) {
                const int c = c0 + 16 * nb + l15;
                *(uint2*)(pbase + c * 64 + 16 * qf + 4 * l4) =
                    make_uint2(pack_bf(acc[qf][nb][0], acc[qf][nb][1]),
                               pack_bf(acc[qf][nb][2], acc[qf][nb][3]));
            }
        }
    }
}

// ---------------------------------------------------------------------------
// reduce: combine 2 KV-half partials, normalize, apply gamma and residual.
// ---------------------------------------------------------------------------
__global__ __launch_bounds__(256) void reduce_kernel(
    const unsigned short* __restrict__ po, const float* __restrict__ mlb,
    const float* __restrict__ x, const float* __restrict__ gamma,
    float* __restrict__ out)
{
    __shared__ float a0l[64], a1l[64];

    const int bq = blockIdx.x >> 2;           // b*64 + qt
    const int cq = blockIdx.x & 3;
    const int b = bq >> 6, qt = bq & 63;
    const int lid0 = bq << 1, lid1 = lid0 | 1;
    const int tid = threadIdx.x;

    if (tid < 64) {
        const float m0 = mlb[(size_t)lid0 * 128 + tid];
        const float l0 = mlb[(size_t)lid0 * 128 + 64 + tid];
        const float m1 = mlb[(size_t)lid1 * 128 + tid];
        const float l1 = mlb[(size_t)lid1 * 128 + 64 + tid];
        const float ms = fmaxf(m0, m1);
        const float w0 = EXP2(m0 - ms), w1 = EXP2(m1 - ms);
        const float inv = gamma[0] / (l0 * w0 + l1 * w1);
        a0l[tid] = w0 * inv;
        a1l[tid] = w1 * inv;
    }
    __syncthreads();

    const int i4 = tid & 15, c16 = tid >> 4;
    const float4 av0 = *(const float4*)&a0l[i4 * 4];
    const float4 av1 = *(const float4*)&a1l[i4 * 4];

#pragma unroll
    for (int cc = 0; cc < 4; ++cc) {
        const int c = (cq << 6) + cc * 16 + c16;
        const uint2 p0 = *(const uint2*)(po + ((size_t)lid0 << 14) + c * 64 + i4 * 4);
        const uint2 p1 = *(const uint2*)(po + ((size_t)lid1 << 14) + c * 64 + i4 * 4);
        const size_t xi = ((size_t)(b * C_ + c)) * N_ + (qt << 6) + i4 * 4;
        const float4 xr = *(const float4*)(x + xi);
        float4 res;
        res.x = bf_lo(p0.x) * av0.x + bf_lo(p1.x) * av1.x + xr.x;
        res.y = bf_hi(p0.x) * av0.y + bf_hi(p1.x) * av1.y + xr.y;
        res.z = bf_lo(p0.y) * av0.z + bf_lo(p1.y) * av1.z + xr.z;
        res.w = bf_hi(p0.y) * av0.w + bf_hi(p1.y) * av1.w + xr.w;
        *(float4*)(out + xi) = res;
    }
}

extern "C" void kernel_launch(void* const* d_in, const int* in_sizes, int n_in,
                              void* d_out, int out_size, void* d_ws, size_t ws_size,
                              hipStream_t stream) {
    (void)in_sizes; (void)n_in; (void)out_size; (void)ws_size;
    const float* x  = (const float*)d_in[0];
    const float* Wq = (const float*)d_in[1];
    const float* bq = (const float*)d_in[2];
    const float* Wk = (const float*)d_in[3];
    const float* bk = (const float*)d_in[4];
    const float* Wv = (const float*)d_in[5];
    const float* bv = (const float*)d_in[6];
    const float* gm = (const float*)d_in[7];
    float* out = (float*)d_out;

    char* ws = (char*)d_ws;
    unsigned short* wb = (unsigned short*)ws;                                // 160 KB
    float*          bb = (float*)(ws + 320 * 256 * 2);                       // 1.25 KB
    unsigned short* qT = (unsigned short*)(ws + 320 * 256 * 2 + 320 * 4);    // 1 MB
    unsigned short* kT = qT + (size_t)B_ * N_ * 32;                          // 1 MB
    unsigned short* vf = kT + (size_t)B_ * N_ * 32;                          // 8 MB (fragment-major)
    unsigned short* po = vf + (size_t)B_ * C_ * N_;                          // 16 MB (512 x 16384 bf16)
    float*         mlb = (float*)(po + (size_t)512 * 16384);                 // 256 KB

    hipLaunchKernelGGL(prep_kernel, dim3(320), dim3(64), 0, stream,
                       Wq, bq, Wk, bk, Wv, bv, wb, bb);
    hipLaunchKernelGGL(proj_kernel, dim3(256), dim3(256), 0, stream,
                       x, wb, bb, qT, kT, vf);
    hipLaunchKernelGGL(attn_part_kernel, dim3(512), dim3(512), 0, stream,
                       qT, kT, vf, po, mlb);
    hipLaunchKernelGGL(reduce_kernel, dim3(1024), dim3(256), 0, stream,
                       po, mlb, x, gm, out);
}